// Round 4
// baseline (154.551 us; speedup 1.0000x reference)
//
#include <hip/hip_runtime.h>

// SymmetryControl: B=16, C=96, H=96, W=96 fp32.
// out[b,c,h,i] = num/den, 6 taps of the same 96-wide row, gated by sigmoid(s[b,:]).
//
// R8 theory: R4-R7 all plateau at 2.0-2.3 TB/s. Smoking gun: VGPR_Count=28 in R7
// despite 8 float3 loads (24 regs) being "issued back-to-back" in source. The
// compiler register-minimized by SINKING the loads into the consume loop ->
// 1-deep pipeline, full latency exposed per pair. ~18 waves/CU x ~768B in flight
// / ~1000cyc latency = 3.5 B/cyc/CU = 2.2 TB/s — exactly the measured wall.
// Fix: (a) sched_barrier(0) between load block and compute block pins all 16
// loads (8 pairs) before any use -> ~48 load VGPRs live, compiler emits
// descending counted vmcnt per pair (never 0 until last pair); (b) nontemporal
// stores for out: x+w (113MB) fit in 256MB L3; current 50% hit rate is output
// pollution — nt stores should cut FETCH_SIZE.
// Row->lane map (verified R6/R7): row = 32 lanes x 3 floats, 2 rows/wave:
//   col i = 3*tl + e
//   shift -24: lane (tl-8)&31,  same elem
//   shift -48: lane (tl-16)&31, same elem
//   shift -72: lane (tl+8)&31,  same elem
//   flip 23-i: lane (7-tl)&31,  elems reversed
//   flip 47-i: lane (15-tl)&31, elems reversed

#define WDIM  96
#define RPB   9216           // rows per batch (C*H)
#define WPB   4              // waves per block (256 threads)
#define PAIRS 8              // row-pairs per wave
#define RPW   (2 * PAIRS)    // 16 rows per wave

typedef float fvec3 __attribute__((ext_vector_type(3)));

__device__ __forceinline__ float bperm(int byteidx, float v) {
    return __int_as_float(__builtin_amdgcn_ds_bpermute(byteidx, __float_as_int(v)));
}

__global__ __launch_bounds__(64 * WPB)
void symctl_kernel(const float* __restrict__ x,
                   const float* __restrict__ s,
                   const float* __restrict__ w,
                   float* __restrict__ out) {
    const int lane = threadIdx.x & 63;
    const int tl   = lane & 31;          // position within 32-lane half
    const int hsel = lane & 32;          // half selector (0 / 32)
    const int h    = lane >> 5;          // row parity within each pair

    const int wid  = blockIdx.x * WPB + (threadIdx.x >> 6);   // global wave id
    // wave covers rows RPW*wid .. RPW*wid+15; lane handles rows RPW*wid + 2k + h
    const int base = (RPW * wid + h) * WDIM + 3 * tl;         // fits 32-bit

    // ---- issue ALL 16 loads back-to-back (12 KB in flight per wave) ----
    fvec3 xa[PAIRS], wa[PAIRS];
#pragma unroll
    for (int k = 0; k < PAIRS; ++k)
        xa[k] = *(const fvec3*)(x + base + k * (2 * WDIM));
#pragma unroll
    for (int k = 0; k < PAIRS; ++k)
        wa[k] = *(const fvec3*)(w + base + k * (2 * WDIM));

    // Hard fence: nothing (incl. these loads) may cross. Prevents the compiler
    // from sinking loads into the consume loop to save registers (the R4-R7
    // 1-deep-pipeline failure mode). Uses of pair k then get descending counted
    // vmcnt waits — only pair 0 ever pays latency.
    __builtin_amdgcn_sched_barrier(0);

    // ---- block-uniform sigmoid gates (64 rows/block, 9216 % 64 == 0) ----
    const int b = (blockIdx.x * (RPW * WPB)) / RPB;           // block-uniform
    const float* sb = s + b * 5;
    const float sg0 = 1.0f / (1.0f + __expf(-sb[0]));
    const float sg1 = 1.0f / (1.0f + __expf(-sb[1]));
    const float sg2 = 1.0f / (1.0f + __expf(-sb[2]));
    const float sg3 = 1.0f / (1.0f + __expf(-sb[3]));
    const float sg4 = 1.0f / (1.0f + __expf(-sb[4]));

    // bpermute byte indices (per-lane constants, stay within own 32-lane half)
    const int i90  = (hsel | ((tl -  8) & 31)) << 2;
    const int i180 = (hsel | ((tl - 16) & 31)) << 2;
    const int i270 = (hsel | ((tl +  8) & 31)) << 2;
    const int f90  = (hsel | (( 7 - tl) & 31)) << 2;
    const int f180 = (hsel | ((15 - tl) & 31)) << 2;

#pragma unroll
    for (int k = 0; k < PAIRS; ++k) {
        const fvec3 xc = xa[k];
        const fvec3 wc = wa[k];

        const float p0 = xc.x * wc.x;
        const float p1 = xc.y * wc.y;
        const float p2 = xc.z * wc.z;

        float n0 = p0,   n1 = p1,   n2 = p2;
        float d0 = wc.x, d1 = wc.y, d2 = wc.z;

        // ---- shift taps: same element, shuffled lane ----
        n0 = fmaf(sg0, bperm(i90,  p0),   n0);
        n1 = fmaf(sg0, bperm(i90,  p1),   n1);
        n2 = fmaf(sg0, bperm(i90,  p2),   n2);
        d0 = fmaf(sg0, bperm(i90,  wc.x), d0);
        d1 = fmaf(sg0, bperm(i90,  wc.y), d1);
        d2 = fmaf(sg0, bperm(i90,  wc.z), d2);

        n0 = fmaf(sg1, bperm(i180, p0),   n0);
        n1 = fmaf(sg1, bperm(i180, p1),   n1);
        n2 = fmaf(sg1, bperm(i180, p2),   n2);
        d0 = fmaf(sg1, bperm(i180, wc.x), d0);
        d1 = fmaf(sg1, bperm(i180, wc.y), d1);
        d2 = fmaf(sg1, bperm(i180, wc.z), d2);

        n0 = fmaf(sg2, bperm(i270, p0),   n0);
        n1 = fmaf(sg2, bperm(i270, p1),   n1);
        n2 = fmaf(sg2, bperm(i270, p2),   n2);
        d0 = fmaf(sg2, bperm(i270, wc.x), d0);
        d1 = fmaf(sg2, bperm(i270, wc.y), d1);
        d2 = fmaf(sg2, bperm(i270, wc.z), d2);

        // ---- flip taps: shuffled lane, elements reversed (out e <- src 2-e) ----
        n0 = fmaf(sg3, bperm(f90,  p2),   n0);
        n1 = fmaf(sg3, bperm(f90,  p1),   n1);
        n2 = fmaf(sg3, bperm(f90,  p0),   n2);
        d0 = fmaf(sg3, bperm(f90,  wc.z), d0);
        d1 = fmaf(sg3, bperm(f90,  wc.y), d1);
        d2 = fmaf(sg3, bperm(f90,  wc.x), d2);

        n0 = fmaf(sg4, bperm(f180, p2),   n0);
        n1 = fmaf(sg4, bperm(f180, p1),   n1);
        n2 = fmaf(sg4, bperm(f180, p0),   n2);
        d0 = fmaf(sg4, bperm(f180, wc.z), d0);
        d1 = fmaf(sg4, bperm(f180, wc.y), d1);
        d2 = fmaf(sg4, bperm(f180, wc.x), d2);

        fvec3 o;
        o.x = n0 * __builtin_amdgcn_rcpf(d0);
        o.y = n1 * __builtin_amdgcn_rcpf(d1);
        o.z = n2 * __builtin_amdgcn_rcpf(d2);
        // nontemporal: keep the output stream from evicting x/w out of L3
        __builtin_nontemporal_store(o, (fvec3*)(out + base + k * (2 * WDIM)));
    }
}

extern "C" void kernel_launch(void* const* d_in, const int* in_sizes, int n_in,
                              void* d_out, int out_size, void* d_ws, size_t ws_size,
                              hipStream_t stream) {
    const float* x = (const float*)d_in[0];
    const float* s = (const float*)d_in[1];
    const float* w = (const float*)d_in[2];
    float* out = (float*)d_out;

    const int n_rows = in_sizes[0] / WDIM;        // 147456 (in_sizes[0] = float count)
    const int waves  = n_rows / RPW;              // 9216
    const int grid   = waves / WPB;               // 2304 blocks of 256 threads

    dim3 block(64 * WPB);
    symctl_kernel<<<grid, block, 0, stream>>>(x, s, w, out);
}